// Round 1
// baseline (25643.130 us; speedup 1.0000x reference)
//
#include <hip/hip_runtime.h>
#include <math.h>

#define BB 4
#define TT 10
#define CIN 64
#define COUT 64
#define HH 96
#define WW 96
#define HWSZ (HH*WW)
#define LL 5

// ---------------- Kernel A: i2h 3x3 conv (pad 1), with reshape remap ----------------
// At scan step t, batch b, i2h comes from flat image q = t*B + b of inputs.reshape(B*T,...)
__global__ void i2h_conv_kernel(const float* __restrict__ x, const float* __restrict__ w,
                                const float* __restrict__ bias, float* __restrict__ out, int t) {
    __shared__ float sw[CIN * 9];
    const int co = blockIdx.y;          // 0..191
    const int b  = blockIdx.z;          // 0..3
    for (int i = threadIdx.x; i < CIN * 9; i += blockDim.x) sw[i] = w[(size_t)co * CIN * 9 + i];
    __syncthreads();
    const int p = blockIdx.x * blockDim.x + threadIdx.x;   // 0..9215
    const int y = p / WW, xx = p % WW;
    const float* src = x + (size_t)(t * BB + b) * CIN * HWSZ;
    float sum = bias[co];
    for (int ci = 0; ci < CIN; ci++) {
        const float* xp = src + (size_t)ci * HWSZ;
        const float* wp = sw + ci * 9;
        #pragma unroll
        for (int ky = 0; ky < 3; ky++) {
            const int yy = y + ky - 1;
            if (yy < 0 || yy >= HH) continue;
            #pragma unroll
            for (int kx = 0; kx < 3; kx++) {
                const int xc = xx + kx - 1;
                if (xc < 0 || xc >= WW) continue;
                sum += xp[yy * WW + xc] * wp[ky * 3 + kx];
            }
        }
    }
    out[((size_t)b * 192 + co) * HWSZ + p] = sum;
}

// ---------------- Kernel B: f1 = tanh(conv5x5(x_t,i2f) + conv5x5(h,h2f)) ----------------
__global__ void f1_kernel(const float* __restrict__ x, const float* __restrict__ h,
                          const float* __restrict__ wi, const float* __restrict__ bi,
                          const float* __restrict__ wh, const float* __restrict__ bh,
                          float* __restrict__ out, int t) {
    __shared__ float swi[CIN * 25];
    __shared__ float swh[CIN * 25];
    const int co = blockIdx.y;          // 0..31
    const int b  = blockIdx.z;
    for (int i = threadIdx.x; i < CIN * 25; i += blockDim.x) {
        swi[i] = wi[(size_t)co * CIN * 25 + i];
        swh[i] = wh[(size_t)co * CIN * 25 + i];
    }
    __syncthreads();
    const int p = blockIdx.x * blockDim.x + threadIdx.x;
    const int y = p / WW, xx = p % WW;
    const float* xs = x + ((size_t)b * TT + t) * CIN * HWSZ;   // x_t = inputs[:, t]
    const float* hs = h + (size_t)b * CIN * HWSZ;
    float sum = bi[co] + bh[co];
    for (int ci = 0; ci < CIN; ci++) {
        const float* xp = xs + (size_t)ci * HWSZ;
        const float* hp = hs + (size_t)ci * HWSZ;
        const float* wip = swi + ci * 25;
        const float* whp = swh + ci * 25;
        #pragma unroll
        for (int ky = 0; ky < 5; ky++) {
            const int yy = y + ky - 2;
            if (yy < 0 || yy >= HH) continue;
            #pragma unroll
            for (int kx = 0; kx < 5; kx++) {
                const int xc = xx + kx - 2;
                if (xc < 0 || xc >= WW) continue;
                const int o = yy * WW + xc;
                const int wo = ky * 5 + kx;
                sum += xp[o] * wip[wo] + hp[o] * whp[wo];
            }
        }
    }
    out[((size_t)b * 32 + co) * HWSZ + p] = tanhf(sum);
}

// ---------------- Kernel C: flows = conv5x5(f1, flows_w) + b ----------------
__global__ void flows_kernel(const float* __restrict__ f1, const float* __restrict__ w,
                             const float* __restrict__ bias, float* __restrict__ out) {
    __shared__ float sw[32 * 25];
    const int co = blockIdx.y;          // 0..9
    const int b  = blockIdx.z;
    for (int i = threadIdx.x; i < 32 * 25; i += blockDim.x) sw[i] = w[(size_t)co * 32 * 25 + i];
    __syncthreads();
    const int p = blockIdx.x * blockDim.x + threadIdx.x;
    const int y = p / WW, xx = p % WW;
    const float* src = f1 + (size_t)b * 32 * HWSZ;
    float sum = bias[co];
    for (int ci = 0; ci < 32; ci++) {
        const float* xp = src + (size_t)ci * HWSZ;
        const float* wp = sw + ci * 25;
        #pragma unroll
        for (int ky = 0; ky < 5; ky++) {
            const int yy = y + ky - 2;
            if (yy < 0 || yy >= HH) continue;
            #pragma unroll
            for (int kx = 0; kx < 5; kx++) {
                const int xc = xx + kx - 2;
                if (xc < 0 || xc >= WW) continue;
                sum += xp[yy * WW + xc] * wp[ky * 5 + kx];
            }
        }
    }
    out[((size_t)b * 10 + co) * HWSZ + p] = sum;
}

// ---------------- Kernel D: bilinear warp of h by -flow ----------------
__global__ void warp_kernel(const float* __restrict__ h, const float* __restrict__ flows,
                            float* __restrict__ out) {
    const int p  = blockIdx.x * blockDim.x + threadIdx.x;
    const int lc = blockIdx.y;          // 0..319  (l*64 + c)
    const int b  = blockIdx.z;
    const int l = lc >> 6, c = lc & 63;
    const int y = p / WW, xx = p % WW;
    const float f0 = -flows[((size_t)b * 10 + l * 2 + 0) * HWSZ + p];
    const float f1v = -flows[((size_t)b * 10 + l * 2 + 1) * HWSZ + p];
    // exactly mirror the reference expression order
    const float nx = 2.0f * ((float)xx + f0) / (float)(WW - 1) - 1.0f;
    const float ny = 2.0f * ((float)y + f1v) / (float)(HH - 1) - 1.0f;
    const float fx = (nx + 1.0f) * (WW * 0.5f) - 0.5f;
    const float fy = (ny + 1.0f) * (HH * 0.5f) - 0.5f;
    const float x0f = floorf(fx), y0f = floorf(fy);
    const float wx = fx - x0f, wy = fy - y0f;
    const int x0 = (int)x0f, y0 = (int)y0f;
    const float* hp = h + ((size_t)b * COUT + c) * HWSZ;
    float v[4];
    #pragma unroll
    for (int k = 0; k < 4; k++) {
        const int yi = y0 + (k >> 1);
        const int xi = x0 + (k & 1);
        const float valid = (xi >= 0 && xi < WW && yi >= 0 && yi < HH) ? 1.0f : 0.0f;
        const int yc = min(max(yi, 0), HH - 1);
        const int xc = min(max(xi, 0), WW - 1);
        v[k] = hp[yc * WW + xc] * valid;
    }
    const float o = v[0] * (1.0f - wx) * (1.0f - wy) + v[1] * wx * (1.0f - wy)
                  + v[2] * (1.0f - wx) * wy          + v[3] * wx * wy;
    out[((size_t)b * (LL * COUT) + lc) * HWSZ + p] = o;
}

// ---------------- Kernel E: h2h = 1x1 conv (320 -> 192), 4 co per thread ----------------
__global__ void h2h_kernel(const float* __restrict__ warped, const float* __restrict__ w,
                           const float* __restrict__ bias, float* __restrict__ out) {
    __shared__ float sw[4 * 320];
    const int cog = blockIdx.y;         // 0..47
    const int b   = blockIdx.z;
    for (int i = threadIdx.x; i < 4 * 320; i += blockDim.x) sw[i] = w[(size_t)(cog * 4) * 320 + i];
    __syncthreads();
    const int p = blockIdx.x * blockDim.x + threadIdx.x;
    float s0 = bias[cog * 4 + 0];
    float s1 = bias[cog * 4 + 1];
    float s2 = bias[cog * 4 + 2];
    float s3 = bias[cog * 4 + 3];
    const float* wp = warped + (size_t)b * 320 * HWSZ + p;
    for (int k = 0; k < 320; k++) {
        const float v = wp[(size_t)k * HWSZ];
        s0 += v * sw[k];
        s1 += v * sw[320 + k];
        s2 += v * sw[640 + k];
        s3 += v * sw[960 + k];
    }
    float* op = out + ((size_t)b * 192 + cog * 4) * HWSZ + p;
    op[0]        = s0;
    op[HWSZ]     = s1;
    op[2 * HWSZ] = s2;
    op[3 * HWSZ] = s3;
}

// ---------------- Kernel F: gates + state update + outputs ----------------
__global__ void gate_kernel(const float* __restrict__ i2h, const float* __restrict__ h2h,
                            float* h, float* __restrict__ outs,
                            float* __restrict__ last_h, int t) {
    const int idx = blockIdx.x * blockDim.x + threadIdx.x;  // over B*64*HW
    const int p = idx % HWSZ;
    const int c = (idx / HWSZ) % COUT;
    const int b = idx / (HWSZ * COUT);
    const size_t base = (size_t)b * 192 * HWSZ + p;
    const float i_r = i2h[base + (size_t)c * HWSZ];
    const float i_u = i2h[base + (size_t)(COUT + c) * HWSZ];
    const float i_m = i2h[base + (size_t)(2 * COUT + c) * HWSZ];
    const float g_r = h2h[base + (size_t)c * HWSZ];
    const float g_u = h2h[base + (size_t)(COUT + c) * HWSZ];
    const float g_m = h2h[base + (size_t)(2 * COUT + c) * HWSZ];
    const float r = 1.0f / (1.0f + expf(-(i_r + g_r)));
    const float u = 1.0f / (1.0f + expf(-(i_u + g_u)));
    const float m = tanhf(i_m + r * g_m);
    const float hv = h[idx];
    const float nh = u * hv + (1.0f - u) * m;
    h[idx] = nh;  // in-place: each thread touches exactly its own element
    outs[(((size_t)b * TT + t) * COUT + c) * HWSZ + p] = nh;
    if (t == TT - 1) last_h[idx] = nh;
}

extern "C" void kernel_launch(void* const* d_in, const int* in_sizes, int n_in,
                              void* d_out, int out_size, void* d_ws, size_t ws_size,
                              hipStream_t stream) {
    const float* inputs  = (const float*)d_in[0];
    const float* i2h_w   = (const float*)d_in[1];
    const float* i2h_b   = (const float*)d_in[2];
    const float* i2f_w   = (const float*)d_in[3];
    const float* i2f_b   = (const float*)d_in[4];
    const float* h2f_w   = (const float*)d_in[5];
    const float* h2f_b   = (const float*)d_in[6];
    const float* flows_w = (const float*)d_in[7];
    const float* flows_b = (const float*)d_in[8];
    const float* ret_w   = (const float*)d_in[9];
    const float* ret_b   = (const float*)d_in[10];

    float* out = (float*)d_out;
    float* ws  = (float*)d_ws;

    // workspace layout (floats)
    float* h      = ws;                       // 4*64*9216   = 2,359,296
    float* i2h_t  = h + 2359296;              // 4*192*9216  = 7,077,888
    float* f1     = i2h_t + 7077888;          // 4*32*9216   = 1,179,648
    float* flows  = f1 + 1179648;             // 4*10*9216   =   368,640
    float* warped = flows + 368640;           // 4*320*9216  = 11,796,480
    float* h2h    = warped + 11796480;        // 4*192*9216  = 7,077,888
    // total ~119.4 MB

    float* outs   = out;                      // (B,T,64,H,W)
    float* last_h = out + (size_t)BB * TT * COUT * HWSZ;

    hipMemsetAsync(h, 0, (size_t)BB * COUT * HWSZ * sizeof(float), stream);

    const int PBLK = HWSZ / 256;  // 36 blocks of 256 threads cover one image plane
    for (int t = 0; t < TT; t++) {
        i2h_conv_kernel<<<dim3(PBLK, 192, BB), 256, 0, stream>>>(inputs, i2h_w, i2h_b, i2h_t, t);
        f1_kernel<<<dim3(PBLK, 32, BB), 256, 0, stream>>>(inputs, h, i2f_w, i2f_b, h2f_w, h2f_b, f1, t);
        flows_kernel<<<dim3(PBLK, 10, BB), 256, 0, stream>>>(f1, flows_w, flows_b, flows);
        warp_kernel<<<dim3(PBLK, LL * COUT, BB), 256, 0, stream>>>(h, flows, warped);
        h2h_kernel<<<dim3(PBLK, 48, BB), 256, 0, stream>>>(warped, ret_w, ret_b, h2h);
        gate_kernel<<<(BB * COUT * HWSZ) / 256, 256, 0, stream>>>(i2h_t, h2h, h, outs, last_h, t);
    }
}

// Round 2
// 7948.076 us; speedup vs baseline: 3.2263x; 3.2263x over previous
//
#include <hip/hip_runtime.h>
#include <math.h>

#define BB 4
#define TT 10
#define CIN 64
#define COUT 64
#define HH 96
#define WW 96
#define HWSZ (HH*WW)
#define LL 5

// ---------------- Kernel A: i2h 3x3 conv (pad 1), reshape remap q = t*B + b ----------------
// Tiled: 32x8 spatial tile, 16 output channels per thread, input tile in LDS.
__global__ __launch_bounds__(256) void i2h_conv_kernel(const float* __restrict__ x,
                                                       const float* __restrict__ w,
                                                       const float* __restrict__ bias,
                                                       float* __restrict__ out, int t) {
    const int tile = blockIdx.x;               // 0..35 : 3 x-tiles * 12 y-tiles
    const int tx0 = (tile % 3) * 32;
    const int ty0 = (tile / 3) * 8;
    const int co0 = blockIdx.y * 16;           // 12 groups -> 192 co
    const int b   = blockIdx.z;
    __shared__ float s[10 * 34];               // (8+2) x (32+2)
    const int tid = threadIdx.x;
    const int tx = tid & 31, ty = tid >> 5;

    float acc[16];
    #pragma unroll
    for (int j = 0; j < 16; j++) acc[j] = bias[co0 + j];

    const float* src = x + (size_t)(t * BB + b) * CIN * HWSZ;

    for (int ci = 0; ci < CIN; ci++) {
        __syncthreads();
        for (int i = tid; i < 340; i += 256) {
            const int r = i / 34, c = i % 34;
            const int gy = ty0 + r - 1, gx = tx0 + c - 1;
            const bool ok = (gy >= 0 && gy < HH && gx >= 0 && gx < WW);
            s[i] = ok ? src[(size_t)ci * HWSZ + gy * WW + gx] : 0.0f;
        }
        __syncthreads();
        float tap[9];
        #pragma unroll
        for (int r = 0; r < 3; r++)
            #pragma unroll
            for (int c = 0; c < 3; c++)
                tap[r * 3 + c] = s[(ty + r) * 34 + tx + c];
        #pragma unroll
        for (int j = 0; j < 16; j++) {
            const float* wp = w + ((size_t)(co0 + j) * CIN + ci) * 9;  // uniform -> s_load
            #pragma unroll
            for (int k = 0; k < 9; k++) acc[j] += tap[k] * wp[k];
        }
    }
    const int p = (ty0 + ty) * WW + tx0 + tx;
    #pragma unroll
    for (int j = 0; j < 16; j++)
        out[((size_t)b * 192 + co0 + j) * HWSZ + p] = acc[j];
}

// ---------------- Kernel B: f1 = tanh(conv5x5(x_t,i2f) + conv5x5(h,h2f)) ----------------
// Tiled: 32x8 tile, 8 co per thread, both input tiles in LDS.
__global__ __launch_bounds__(256) void f1_kernel(const float* __restrict__ x,
                                                 const float* __restrict__ h,
                                                 const float* __restrict__ wi, const float* __restrict__ bi,
                                                 const float* __restrict__ wh, const float* __restrict__ bh,
                                                 float* __restrict__ out, int t) {
    const int tile = blockIdx.x;
    const int tx0 = (tile % 3) * 32;
    const int ty0 = (tile / 3) * 8;
    const int co0 = blockIdx.y * 8;            // 4 groups -> 32 co
    const int b   = blockIdx.z;
    __shared__ float sx[12 * 36];              // (8+4) x (32+4)
    __shared__ float sh[12 * 36];
    const int tid = threadIdx.x;
    const int tx = tid & 31, ty = tid >> 5;

    float acc[8];
    #pragma unroll
    for (int j = 0; j < 8; j++) acc[j] = bi[co0 + j] + bh[co0 + j];

    const float* xs = x + ((size_t)b * TT + t) * CIN * HWSZ;   // x_t = inputs[:, t]
    const float* hs = h + (size_t)b * CIN * HWSZ;

    for (int ci = 0; ci < CIN; ci++) {
        __syncthreads();
        for (int i = tid; i < 432; i += 256) {
            const int r = i / 36, c = i % 36;
            const int gy = ty0 + r - 2, gx = tx0 + c - 2;
            const bool ok = (gy >= 0 && gy < HH && gx >= 0 && gx < WW);
            const int o = gy * WW + gx;
            sx[i] = ok ? xs[(size_t)ci * HWSZ + o] : 0.0f;
            sh[i] = ok ? hs[(size_t)ci * HWSZ + o] : 0.0f;
        }
        __syncthreads();
        float tapx[25], taph[25];
        #pragma unroll
        for (int r = 0; r < 5; r++)
            #pragma unroll
            for (int c = 0; c < 5; c++) {
                tapx[r * 5 + c] = sx[(ty + r) * 36 + tx + c];
                taph[r * 5 + c] = sh[(ty + r) * 36 + tx + c];
            }
        #pragma unroll
        for (int j = 0; j < 8; j++) {
            const float* wp = wi + ((size_t)(co0 + j) * CIN + ci) * 25;  // uniform
            const float* wq = wh + ((size_t)(co0 + j) * CIN + ci) * 25;  // uniform
            #pragma unroll
            for (int k = 0; k < 25; k++) acc[j] += tapx[k] * wp[k] + taph[k] * wq[k];
        }
    }
    const int p = (ty0 + ty) * WW + tx0 + tx;
    #pragma unroll
    for (int j = 0; j < 8; j++)
        out[((size_t)b * 32 + co0 + j) * HWSZ + p] = tanhf(acc[j]);
}

// ---------------- Kernel C: flows = conv5x5(f1, flows_w) + b ----------------
__global__ __launch_bounds__(256) void flows_kernel(const float* __restrict__ f1,
                                                    const float* __restrict__ w,
                                                    const float* __restrict__ bias,
                                                    float* __restrict__ out) {
    const int tile = blockIdx.x;
    const int tx0 = (tile % 3) * 32;
    const int ty0 = (tile / 3) * 8;
    const int b   = blockIdx.z;
    __shared__ float s[12 * 36];
    const int tid = threadIdx.x;
    const int tx = tid & 31, ty = tid >> 5;

    float acc[10];
    #pragma unroll
    for (int j = 0; j < 10; j++) acc[j] = bias[j];

    const float* src = f1 + (size_t)b * 32 * HWSZ;
    for (int ci = 0; ci < 32; ci++) {
        __syncthreads();
        for (int i = tid; i < 432; i += 256) {
            const int r = i / 36, c = i % 36;
            const int gy = ty0 + r - 2, gx = tx0 + c - 2;
            const bool ok = (gy >= 0 && gy < HH && gx >= 0 && gx < WW);
            s[i] = ok ? src[(size_t)ci * HWSZ + gy * WW + gx] : 0.0f;
        }
        __syncthreads();
        float tap[25];
        #pragma unroll
        for (int r = 0; r < 5; r++)
            #pragma unroll
            for (int c = 0; c < 5; c++)
                tap[r * 5 + c] = s[(ty + r) * 36 + tx + c];
        #pragma unroll
        for (int j = 0; j < 10; j++) {
            const float* wp = w + ((size_t)j * 32 + ci) * 25;  // uniform
            #pragma unroll
            for (int k = 0; k < 25; k++) acc[j] += tap[k] * wp[k];
        }
    }
    const int p = (ty0 + ty) * WW + tx0 + tx;
    #pragma unroll
    for (int j = 0; j < 10; j++)
        out[((size_t)b * 10 + j) * HWSZ + p] = acc[j];
}

// ---------------- Kernel D: bilinear warp of h by -flow; coords computed once per pixel ----------------
__global__ __launch_bounds__(256) void warp_kernel(const float* __restrict__ h,
                                                   const float* __restrict__ flows,
                                                   float* __restrict__ out) {
    const int p = blockIdx.x * 256 + threadIdx.x;  // plane index
    const int l = blockIdx.y;                      // 0..4
    const int b = blockIdx.z;
    const int y = p / WW, xx = p % WW;
    const float f0  = -flows[((size_t)b * 10 + l * 2 + 0) * HWSZ + p];
    const float f1v = -flows[((size_t)b * 10 + l * 2 + 1) * HWSZ + p];
    const float nx = 2.0f * ((float)xx + f0)  / (float)(WW - 1) - 1.0f;
    const float ny = 2.0f * ((float)y  + f1v) / (float)(HH - 1) - 1.0f;
    const float fx = (nx + 1.0f) * (WW * 0.5f) - 0.5f;
    const float fy = (ny + 1.0f) * (HH * 0.5f) - 0.5f;
    const float x0f = floorf(fx), y0f = floorf(fy);
    const float wx = fx - x0f, wy = fy - y0f;
    const int x0 = (int)x0f, y0 = (int)y0f;

    int   off[4];
    float wgt[4];
    #pragma unroll
    for (int k = 0; k < 4; k++) {
        const int yi = y0 + (k >> 1);
        const int xi = x0 + (k & 1);
        const bool ok = (xi >= 0 && xi < WW && yi >= 0 && yi < HH);
        const int yc = min(max(yi, 0), HH - 1);
        const int xc = min(max(xi, 0), WW - 1);
        off[k] = yc * WW + xc;
        const float wk = ((k & 1) ? wx : 1.0f - wx) * ((k >> 1) ? wy : 1.0f - wy);
        wgt[k] = ok ? wk : 0.0f;
    }
    const float* hp = h + (size_t)b * COUT * HWSZ;
    float* op = out + ((size_t)b * (LL * COUT) + l * COUT) * HWSZ + p;
    for (int c = 0; c < COUT; c++) {
        const float* hc = hp + (size_t)c * HWSZ;
        const float o = hc[off[0]] * wgt[0] + hc[off[1]] * wgt[1]
                      + hc[off[2]] * wgt[2] + hc[off[3]] * wgt[3];
        op[(size_t)c * HWSZ] = o;
    }
}

// ---------------- Kernel E: h2h = 1x1 conv (320 -> 192), 16 co per thread ----------------
__global__ __launch_bounds__(256) void h2h_kernel(const float* __restrict__ warped,
                                                  const float* __restrict__ w,
                                                  const float* __restrict__ bias,
                                                  float* __restrict__ out) {
    const int p   = blockIdx.x * 256 + threadIdx.x;
    const int co0 = blockIdx.y * 16;               // 12 groups -> 192
    const int b   = blockIdx.z;
    float acc[16];
    #pragma unroll
    for (int j = 0; j < 16; j++) acc[j] = bias[co0 + j];
    const float* wp0 = warped + (size_t)b * 320 * HWSZ + p;
    for (int k = 0; k < 320; k++) {
        const float v = wp0[(size_t)k * HWSZ];
        #pragma unroll
        for (int j = 0; j < 16; j++) acc[j] += v * w[(size_t)(co0 + j) * 320 + k];  // uniform wt
    }
    float* op = out + ((size_t)b * 192 + co0) * HWSZ + p;
    #pragma unroll
    for (int j = 0; j < 16; j++) op[(size_t)j * HWSZ] = acc[j];
}

// ---------------- Kernel F: gates + state update + outputs ----------------
__global__ __launch_bounds__(256) void gate_kernel(const float* __restrict__ i2h,
                                                   const float* __restrict__ h2h,
                                                   float* h, float* __restrict__ outs,
                                                   float* __restrict__ last_h, int t) {
    const int idx = blockIdx.x * 256 + threadIdx.x;  // over B*64*HW
    const int p = idx % HWSZ;
    const int c = (idx / HWSZ) % COUT;
    const int b = idx / (HWSZ * COUT);
    const size_t base = (size_t)b * 192 * HWSZ + p;
    const float i_r = i2h[base + (size_t)c * HWSZ];
    const float i_u = i2h[base + (size_t)(COUT + c) * HWSZ];
    const float i_m = i2h[base + (size_t)(2 * COUT + c) * HWSZ];
    const float g_r = h2h[base + (size_t)c * HWSZ];
    const float g_u = h2h[base + (size_t)(COUT + c) * HWSZ];
    const float g_m = h2h[base + (size_t)(2 * COUT + c) * HWSZ];
    const float r = 1.0f / (1.0f + expf(-(i_r + g_r)));
    const float u = 1.0f / (1.0f + expf(-(i_u + g_u)));
    const float m = tanhf(i_m + r * g_m);
    const float hv = h[idx];
    const float nh = u * hv + (1.0f - u) * m;
    h[idx] = nh;
    outs[(((size_t)b * TT + t) * COUT + c) * HWSZ + p] = nh;
    if (t == TT - 1) last_h[idx] = nh;
}

extern "C" void kernel_launch(void* const* d_in, const int* in_sizes, int n_in,
                              void* d_out, int out_size, void* d_ws, size_t ws_size,
                              hipStream_t stream) {
    const float* inputs  = (const float*)d_in[0];
    const float* i2h_w   = (const float*)d_in[1];
    const float* i2h_b   = (const float*)d_in[2];
    const float* i2f_w   = (const float*)d_in[3];
    const float* i2f_b   = (const float*)d_in[4];
    const float* h2f_w   = (const float*)d_in[5];
    const float* h2f_b   = (const float*)d_in[6];
    const float* flows_w = (const float*)d_in[7];
    const float* flows_b = (const float*)d_in[8];
    const float* ret_w   = (const float*)d_in[9];
    const float* ret_b   = (const float*)d_in[10];

    float* out = (float*)d_out;
    float* ws  = (float*)d_ws;

    // workspace layout (floats)
    float* h      = ws;                       // 4*64*9216   = 2,359,296
    float* i2h_t  = h + 2359296;              // 4*192*9216  = 7,077,888
    float* f1     = i2h_t + 7077888;          // 4*32*9216   = 1,179,648
    float* flows  = f1 + 1179648;             // 4*10*9216   =   368,640
    float* warped = flows + 368640;           // 4*320*9216  = 11,796,480
    float* h2h    = warped + 11796480;        // 4*192*9216  = 7,077,888

    float* outs   = out;                      // (B,T,64,H,W)
    float* last_h = out + (size_t)BB * TT * COUT * HWSZ;

    hipMemsetAsync(h, 0, (size_t)BB * COUT * HWSZ * sizeof(float), stream);

    const int PBLK = HWSZ / 256;  // 36
    for (int t = 0; t < TT; t++) {
        i2h_conv_kernel<<<dim3(36, 12, BB), 256, 0, stream>>>(inputs, i2h_w, i2h_b, i2h_t, t);
        f1_kernel<<<dim3(36, 4, BB), 256, 0, stream>>>(inputs, h, i2f_w, i2f_b, h2f_w, h2f_b, f1, t);
        flows_kernel<<<dim3(36, 1, BB), 256, 0, stream>>>(f1, flows_w, flows_b, flows);
        warp_kernel<<<dim3(PBLK, LL, BB), 256, 0, stream>>>(h, flows, warped);
        h2h_kernel<<<dim3(PBLK, 12, BB), 256, 0, stream>>>(warped, ret_w, ret_b, h2h);
        gate_kernel<<<(BB * COUT * HWSZ) / 256, 256, 0, stream>>>(i2h_t, h2h, h, outs, last_h, t);
    }
}